// Round 6
// baseline (63.416 us; speedup 1.0000x reference)
//
#include <hip/hip_runtime.h>
#include <hip/hip_bf16.h>
#include <math.h>

#define GRIDN 1024
#define NAGENTS 262144
#define CCH 8
#define HIDDEN 64
#define DT 0.1f
#define DECAYF 0.99f
#define SENSOR_LEN 3.0f
// cos(0.6), sin(0.6)
#define COS_SA 0.82533561490967829724f
#define SIN_SA 0.56464247339503535720f

typedef __attribute__((ext_vector_type(8))) short short8;
typedef __attribute__((ext_vector_type(2))) _Float16 half2v;

// packed 2-way f16 dot with f32 accumulate: v_dot2_f32_f16
__device__ __forceinline__ float dot2f(unsigned a, unsigned b, float c) {
#if __has_builtin(__builtin_amdgcn_fdot2)
    return __builtin_amdgcn_fdot2(__builtin_bit_cast(half2v, a),
                                  __builtin_bit_cast(half2v, b), c, false);
#else
    half2v ha = __builtin_bit_cast(half2v, a), hb = __builtin_bit_cast(half2v, b);
    return c + (float)ha.x * (float)hb.x + (float)ha.y * (float)hb.y;
#endif
}

__device__ __forceinline__ unsigned packh(float a, float b) {
    _Float16 ha = (_Float16)a, hb = (_Float16)b;
    unsigned short ua = __builtin_bit_cast(unsigned short, ha);
    unsigned short ub = __builtin_bit_cast(unsigned short, hb);
    return (unsigned)ua | ((unsigned)ub << 16);
}

// tanh(x) = (2^(2x*log2e) - 1) / (2^(2x*log2e) + 1), clamped so exp2 can't overflow
__device__ __forceinline__ float fast_tanh(float x) {
    float xc = fminf(fmaxf(x, -9.0f), 9.0f);
    float t = __builtin_amdgcn_exp2f(xc * 2.88539008177792681472f);  // 2*log2(e)
    return (t - 1.0f) * __builtin_amdgcn_rcpf(t + 1.0f);
}

// BT[x][y][c] = 3x3 torus box sum of channel c at (x,y), stored f16.
// 2 cells per thread (x and x+1, same y): rows x-1..x+2 shared, 6 taps/cell
// instead of 9 (TA-request cut). Fused: winner init; block 0 packs weights.
__global__ void __launch_bounds__(256) k_boxT(const float* __restrict__ lat,
                                              _Float16* __restrict__ BT,
                                              int* __restrict__ winner,
                                              const float* __restrict__ W1,
                                              const float* __restrict__ W2,
                                              unsigned* __restrict__ W1p,
                                              unsigned* __restrict__ W2p) {
    if (blockIdx.x == 0) {
        for (int t = threadIdx.x; t < 768 + 512; t += 256) {
            if (t < 768) {
                int p = t >> 6, j = t & 63;
                W1p[t] = packh(W1[(2 * p) * HIDDEN + j], W1[(2 * p + 1) * HIDDEN + j]);
            } else {
                int q = t - 768;
                int pg = q >> 4, k = q & 15;
                unsigned v = 0;
                if (k < 10) v = packh(W2[(2 * pg) * 10 + k], W2[(2 * pg + 1) * 10 + k]);
                W2p[q] = v;
            }
        }
    }
    int b = blockIdx.x;
    int x = (b >> 2) * 2;                       // even row of the pair
    int y = (b & 3) * 256 + threadIdx.x;
    int idx0 = (x << 10) + y;
    int idx1 = idx0 + GRIDN;                    // (x+1, y), x+1 <= 1023
    winner[idx0] = -1;
    winner[idx1] = -1;

    int xm = (x + GRIDN - 1) & (GRIDN - 1);
    int xp2 = (x + 2) & (GRIDN - 1);
    int ym = (y + GRIDN - 1) & (GRIDN - 1), yp = (y + 1) & (GRIDN - 1);

    _Float16 out0[CCH], out1[CCH];
#pragma unroll
    for (int c = 0; c < CCH; ++c) {
        const float* L = lat + (size_t)c * GRIDN * GRIDN;
        const float* ra = L + xm * GRIDN;
        const float* rb = L + x * GRIDN;
        const float* rc = L + (x + 1) * GRIDN;
        const float* rd = L + xp2 * GRIDN;
        float sa = ra[ym] + ra[y] + ra[yp];
        float sb = rb[ym] + rb[y] + rb[yp];
        float sc = rc[ym] + rc[y] + rc[yp];
        float sd = rd[ym] + rd[y] + rd[yp];
        out0[c] = (_Float16)(sa + sb + sc);
        out1[c] = (_Float16)(sb + sc + sd);
    }
    *(short8*)(BT + (size_t)idx0 * CCH) = *(const short8*)out0;
    *(short8*)(BT + (size_t)idx1 * CCH) = *(const short8*)out1;
}

// Block = 256 threads = 4 waves; block handles 64 agents (agent = base + lane).
// Gather dedupe: wave s (s<3) gathers ONLY sensor s for all 64 agents into
// LDS sens[12][64] (conflict-free: lane stride 4B); wave 3 does the winner
// atomicMax meanwhile. After one barrier every wave reads all 24 f16 inputs
// from LDS. Hidden-slice split by wave (SGPR-uniform weight addresses).
__global__ void __launch_bounds__(256) k_agent(
    const float* __restrict__ pos, const float* __restrict__ vel,
    const _Float16* __restrict__ BT,
    const unsigned* __restrict__ W1p, const float* __restrict__ b1,
    const unsigned* __restrict__ W2p, const float* __restrict__ b2,
    float* __restrict__ out_pos, float* __restrict__ out_vel,
    float* __restrict__ dp, int* __restrict__ winner) {
    __shared__ unsigned sens[12][64];
    __shared__ float part[4][64][13];  // 13-pad: stride coprime with 32 banks

    int lane = threadIdx.x & 63;
    int wq = __builtin_amdgcn_readfirstlane(threadIdx.x >> 6);  // SGPR slice id
    int i = blockIdx.x * 64 + lane;  // agent

    float px = pos[i], py = pos[i + NAGENTS];

    if (wq < 3) {
        float vx = vel[i], vy = vel[i + NAGENTS];
        float r2 = vx * vx + vy * vy;
        float ct, st;
        if (r2 > 0.f) {
            float inv = rsqrtf(r2);
            ct = vx * inv;
            st = vy * inv;
        } else {
            ct = 1.f;  // atan2(0,0) = 0
            st = 0.f;
        }
        // my sensor: wq==0 front, wq==1 left(+0.6), wq==2 right(-0.6)
        float dx, dy;
        if (wq == 0)      { dx = ct;                        dy = st; }
        else if (wq == 1) { dx = ct * COS_SA - st * SIN_SA; dy = st * COS_SA + ct * SIN_SA; }
        else              { dx = ct * COS_SA + st * SIN_SA; dy = st * COS_SA - ct * SIN_SA; }

        int gx = ((int)rintf(px + SENSOR_LEN * dx) + GRIDN) & (GRIDN - 1);
        int gy = ((int)rintf(py + SENSOR_LEN * dy) + GRIDN) & (GRIDN - 1);
        uint4 u = *(const uint4*)(BT + ((size_t)(gx << 10) + gy) * CCH);
        sens[wq * 4 + 0][lane] = u.x;
        sens[wq * 4 + 1][lane] = u.y;
        sens[wq * 4 + 2][lane] = u.z;
        sens[wq * 4 + 3][lane] = u.w;
    } else {
        int wx = (int)rintf(px) & (GRIDN - 1);
        int wy = (int)rintf(py) & (GRIDN - 1);
        atomicMax(&winner[(wx << 10) + wy], i);
    }
    __syncthreads();

    // xk[p] = f16 pair (x[2p], x[2p+1]); x = [front8, left8, right8]
    unsigned xk[12];
#pragma unroll
    for (int p = 0; p < 12; ++p) xk[p] = sens[p][lane];

    // layer 1: h[jj] = b1[wq*16+jj] + sum_p dot2(xk[p], W1pair[p][wq*16+jj])
    float h[16];
    {
        const float4* b1v = (const float4*)(b1 + wq * 16);
#pragma unroll
        for (int q = 0; q < 4; ++q) {
            float4 b = b1v[q];
            h[q * 4 + 0] = b.x; h[q * 4 + 1] = b.y;
            h[q * 4 + 2] = b.z; h[q * 4 + 3] = b.w;
        }
    }
#pragma unroll
    for (int p = 0; p < 12; ++p) {
        unsigned xp = xk[p];
        const unsigned* wrow = W1p + p * HIDDEN + wq * 16;  // wave-uniform
#pragma unroll
        for (int jj = 0; jj < 16; ++jj) h[jj] = dot2f(xp, wrow[jj], h[jj]);
    }

    // layer 2 partial: tanh, pack to f16 pairs, dot2 against pre-paired W2
    unsigned hp[8];
#pragma unroll
    for (int p = 0; p < 8; ++p)
        hp[p] = packh(fast_tanh(h[2 * p]), fast_tanh(h[2 * p + 1]));

    float o[2 + CCH];
#pragma unroll
    for (int k = 0; k < 2 + CCH; ++k) o[k] = 0.f;
#pragma unroll
    for (int p = 0; p < 8; ++p) {
        const unsigned* w2row = W2p + (wq * 8 + p) * 16;  // wave-uniform
#pragma unroll
        for (int k = 0; k < 2 + CCH; ++k) o[k] = dot2f(hp[p], w2row[k], o[k]);
    }

#pragma unroll
    for (int k = 0; k < 2 + CCH; ++k) part[wq][lane][k] = o[k];
    __syncthreads();

    // epilogue duties split by wave
    if (wq == 0) {
        float s0 = part[0][lane][0] + part[1][lane][0] + part[2][lane][0] + part[3][lane][0] + b2[0];
        float s1 = part[0][lane][1] + part[1][lane][1] + part[2][lane][1] + part[3][lane][1] + b2[1];
        float npx = px + s0 * DT;
        if (npx >= (float)GRIDN) npx -= (float)GRIDN;
        if (npx < 0.f) npx += (float)GRIDN;
        float npy = py + s1 * DT;
        if (npy >= (float)GRIDN) npy -= (float)GRIDN;
        if (npy < 0.f) npy += (float)GRIDN;
        out_pos[i] = npx;
        out_pos[i + NAGENTS] = npy;
        out_vel[i] = s0;
        out_vel[i + NAGENTS] = s1;
    } else if (wq == 1) {
        float d0 = part[0][lane][2] + part[1][lane][2] + part[2][lane][2] + part[3][lane][2] + b2[2];
        float d1 = part[0][lane][3] + part[1][lane][3] + part[2][lane][3] + part[3][lane][3] + b2[3];
        float d2 = part[0][lane][4] + part[1][lane][4] + part[2][lane][4] + part[3][lane][4] + b2[4];
        float d3 = part[0][lane][5] + part[1][lane][5] + part[2][lane][5] + part[3][lane][5] + b2[5];
        *(float4*)(dp + (size_t)i * CCH) = make_float4(d0, d1, d2, d3);
    } else if (wq == 2) {
        float d4 = part[0][lane][6] + part[1][lane][6] + part[2][lane][6] + part[3][lane][6] + b2[6];
        float d5 = part[0][lane][7] + part[1][lane][7] + part[2][lane][7] + part[3][lane][7] + b2[7];
        float d6 = part[0][lane][8] + part[1][lane][8] + part[2][lane][8] + part[3][lane][8] + b2[8];
        float d7 = part[0][lane][9] + part[1][lane][9] + part[2][lane][9] + part[3][lane][9] + b2[9];
        *(float4*)(dp + (size_t)i * CCH + 4) = make_float4(d4, d5, d6, d7);
    }
}

__global__ void __launch_bounds__(256) k_update(const float* __restrict__ lat,
                                                const int* __restrict__ winner,
                                                const float* __restrict__ dp,
                                                float* __restrict__ out_lat) {
    int idx = blockIdx.x * blockDim.x + threadIdx.x;  // cell index
    int w = winner[idx];
    float d[CCH];
    if (w >= 0) {
        const float4* dpp = (const float4*)(dp + (size_t)w * CCH);
        float4 a = dpp[0], b = dpp[1];
        d[0] = a.x; d[1] = a.y; d[2] = a.z; d[3] = a.w;
        d[4] = b.x; d[5] = b.y; d[6] = b.z; d[7] = b.w;
    }
#pragma unroll
    for (int c = 0; c < CCH; ++c) {
        size_t off = (size_t)c * GRIDN * GRIDN + idx;
        float v = lat[off];
        if (w >= 0) v = fmaxf(v + DT * d[c], 0.f);
        out_lat[off] = v * DECAYF;
    }
}

extern "C" void kernel_launch(void* const* d_in, const int* in_sizes, int n_in,
                              void* d_out, int out_size, void* d_ws, size_t ws_size,
                              hipStream_t stream) {
    const float* pos = (const float*)d_in[0];
    const float* vel = (const float*)d_in[1];
    const float* lat = (const float*)d_in[2];
    const float* W1  = (const float*)d_in[3];
    const float* b1  = (const float*)d_in[4];
    const float* W2  = (const float*)d_in[5];
    const float* b2  = (const float*)d_in[6];

    float* out      = (float*)d_out;
    float* out_pos  = out;                 // (2, N)
    float* out_vel  = out + 2 * NAGENTS;   // (2, N)
    float* out_lat  = out + 4 * NAGENTS;   // (C, G, G)

    char* ws = (char*)d_ws;
    int*       winner = (int*)ws;                       // 4 MB
    float*     dp     = (float*)(ws + (4 << 20));       // 8 MB
    _Float16*  BT     = (_Float16*)(ws + (12 << 20));   // 16 MB
    unsigned*  W1p    = (unsigned*)(ws + (28 << 20));   // 3 KB
    unsigned*  W2p    = (unsigned*)(ws + (28 << 20) + 4096);  // 2 KB

    const int ncell = GRIDN * GRIDN;

    k_boxT<<<ncell / 2 / 256, 256, 0, stream>>>(lat, BT, winner, W1, W2, W1p, W2p);
    k_agent<<<NAGENTS / 64, 256, 0, stream>>>(pos, vel, BT, W1p, b1, W2p, b2,
                                              out_pos, out_vel, dp, winner);
    k_update<<<ncell / 256, 256, 0, stream>>>(lat, winner, dp, out_lat);
}